// Round 2
// baseline (828.899 us; speedup 1.0000x reference)
//
#include <hip/hip_runtime.h>

typedef _Float16 half8 __attribute__((ext_vector_type(8)));
typedef float f32x4 __attribute__((ext_vector_type(4)));

#define NATOMS 40000
#define D_AEV  384

constexpr int S_NUM = 4, E_NUM = 8;
constexpr int H1W = 160, H2W = 128, H3W = 96;
constexpr float ALPHA = 0.1f;

// ---- workspace layout (bytes) ----
constexpr size_t OFF_CNT    = 0;
constexpr size_t OFF_BUCKET = 256;
constexpr size_t OFF_AEVH   = OFF_BUCKET + (size_t)S_NUM * NATOMS * 4;      // 640256
constexpr size_t OFF_WT1    = OFF_AEVH + (size_t)NATOMS * D_AEV * 2;        // +30.72MB
constexpr size_t OFF_WT2    = OFF_WT1 + (size_t)S_NUM * E_NUM * H1W * D_AEV * 2;
constexpr size_t OFF_WT3    = OFF_WT2 + (size_t)S_NUM * E_NUM * H2W * H1W * 2;

// ---------------- pre-kernels ----------------

__global__ void bucket_kernel(const int* __restrict__ species, int* __restrict__ counts,
                              int* __restrict__ bucket) {
    int i = blockIdx.x * 256 + threadIdx.x;
    if (i >= NATOMS) return;
    int s = species[i];
    int pos = atomicAdd(&counts[s], 1);
    bucket[s * NATOMS + pos] = i;
}

__global__ void cvt_aev_kernel(const float* __restrict__ in, _Float16* __restrict__ out) {
    int i = blockIdx.x * 256 + threadIdx.x;        // one 8-float chunk per thread
    if (i >= NATOMS * D_AEV / 8) return;
    const float4* p = (const float4*)in + (size_t)i * 2;
    float4 a = p[0], b = p[1];
    half8 h;
    h[0] = (_Float16)a.x; h[1] = (_Float16)a.y; h[2] = (_Float16)a.z; h[3] = (_Float16)a.w;
    h[4] = (_Float16)b.x; h[5] = (_Float16)b.y; h[6] = (_Float16)b.z; h[7] = (_Float16)b.w;
    *(half8*)&out[(size_t)i * 8] = h;
}

// in: [nmat][R][C] fp32  ->  out: [nmat][C][R] fp16   (R,C multiples of 32)
__global__ void transpose_cvt_kernel(const float* __restrict__ in, _Float16* __restrict__ out,
                                     int R, int C) {
    __shared__ float t[32][33];
    int m = blockIdx.z;
    const float* src = in + (size_t)m * R * C;
    _Float16* dst = out + (size_t)m * R * C;
    int c0 = blockIdx.x * 32, r0 = blockIdx.y * 32;
    int tx = threadIdx.x, ty = threadIdx.y;
#pragma unroll
    for (int j = 0; j < 32; j += 8)
        t[ty + j][tx] = src[(size_t)(r0 + ty + j) * C + c0 + tx];
    __syncthreads();
#pragma unroll
    for (int j = 0; j < 32; j += 8)
        dst[(size_t)(c0 + ty + j) * R + r0 + tx] = (_Float16)t[tx][ty + j];
}

// ---------------- main fused MLP kernel ----------------

struct LdsT {
    _Float16 X[2][4 * 64 * 8];          // dbuf: [kg4][atom64][8]   8 KB
    _Float16 W[2][4 * H1W * 8];         // dbuf: [kg4][feat<=160][8] 20 KB
    _Float16 H1[(H1W / 8) * 64 * 8];    // [kg20][atom64][8]        20 KB
    _Float16 H2[(H2W / 8) * 64 * 8];    // [kg16][atom64][8]        16 KB
    float eacc[64];
    int idx[64];
};

__device__ __forceinline__ float celu_f(float x) {
    return x > 0.f ? x : fmaf(ALPHA, __expf(x * (1.f / ALPHA)), -ALPHA);
}

__device__ __forceinline__ f32x4 mfma16(half8 a, half8 b, f32x4 c) {
    return __builtin_amdgcn_mfma_f32_16x16x32_f16(a, b, c, 0, 0, 0);
}

// Swapped-operand layer: A = weights (OUTW x K), B = activations (K x 64 atoms).
// C[row=feature][col=atom].  Wave grid 2x2: wf = feature half, wa = atom half.
template <int OUTW, int KDIM, bool FIRST, bool LAST>
__device__ __forceinline__ void do_layer(
    LdsT& L,
    const _Float16* __restrict__ wsrc,   // weights [OUTW][KDIM] fp16 (transposed), this (s,e)
    const _Float16* __restrict__ xsrc,   // FIRST: per-thread aevh row base
    const _Float16* __restrict__ Hin,    // !FIRST: LDS activations [KDIM/8][64][8]
    _Float16* __restrict__ Hout,         // !LAST: LDS out
    const float* __restrict__ bias,      // + se*OUTW
    const float* __restrict__ w4,        // LAST: + se*H3W
    int tid) {
    constexpr int NK = KDIM / 32;
    constexpr int NFT = OUTW / 32;           // feature 16-tiles per wave
    constexpr int WTASK = OUTW * 4;          // 16B lane-loads per W k-slice
    constexpr int NWIT = (WTASK + 255) / 256;

    const int lane = tid & 63, wave = tid >> 6;
    const int wf = wave >> 1, wa = wave & 1;
    const int l15 = lane & 15, l4 = lane >> 4;
    const int fbase = wf * (OUTW / 2);
    const int abase = wa * 32;

    f32x4 acc[NFT][2];
#pragma unroll
    for (int f = 0; f < NFT; ++f) {
        acc[f][0] = (f32x4){0.f, 0.f, 0.f, 0.f};
        acc[f][1] = (f32x4){0.f, 0.f, 0.f, 0.f};
    }

    uint4 wreg[NWIT];
    uint4 xreg;

    auto load_stage = [&](int kk) {
#pragma unroll
        for (int j = 0; j < NWIT; ++j) {
            int i = tid + j * 256;
            if (i < WTASK) {
                int o = i >> 2, kg = i & 3;
                wreg[j] = *(const uint4*)&wsrc[(size_t)o * KDIM + kk * 32 + kg * 8];
            }
        }
        if (FIRST) xreg = *(const uint4*)&xsrc[kk * 32 + (tid & 3) * 8];
    };
    auto write_stage = [&](int buf) {
#pragma unroll
        for (int j = 0; j < NWIT; ++j) {
            int i = tid + j * 256;
            if (i < WTASK) {
                int o = i >> 2, kg = i & 3;
                *(uint4*)&L.W[buf][(kg * OUTW + o) * 8] = wreg[j];
            }
        }
        if (FIRST) *(uint4*)&L.X[buf][((tid & 3) * 64 + (tid >> 2)) * 8] = xreg;
    };

    load_stage(0);
    write_stage(0);
    __syncthreads();

    for (int kk = 0; kk < NK; ++kk) {
        int cur = kk & 1;
        if (kk + 1 < NK) load_stage(kk + 1);
        half8 bfr0, bfr1;
        if (FIRST) {
            bfr0 = *(const half8*)&L.X[cur][(l4 * 64 + abase + l15) * 8];
            bfr1 = *(const half8*)&L.X[cur][(l4 * 64 + abase + 16 + l15) * 8];
        } else {
            bfr0 = *(const half8*)&Hin[((kk * 4 + l4) * 64 + abase + l15) * 8];
            bfr1 = *(const half8*)&Hin[((kk * 4 + l4) * 64 + abase + 16 + l15) * 8];
        }
#pragma unroll
        for (int f = 0; f < NFT; ++f) {
            half8 afr = *(const half8*)&L.W[cur][(l4 * OUTW + fbase + f * 16 + l15) * 8];
            acc[f][0] = mfma16(afr, bfr0, acc[f][0]);
            acc[f][1] = mfma16(afr, bfr1, acc[f][1]);
        }
        __syncthreads();
        if (kk + 1 < NK) write_stage((kk + 1) & 1);
        __syncthreads();
    }

    if (!LAST) {
#pragma unroll
        for (int f = 0; f < NFT; ++f) {
#pragma unroll
            for (int t2 = 0; t2 < 2; ++t2) {
                int atom = abase + t2 * 16 + l15;
#pragma unroll
                for (int r = 0; r < 4; ++r) {
                    int feat = fbase + f * 16 + l4 * 4 + r;
                    float v = acc[f][t2][r] + bias[feat];
                    v = celu_f(v);
                    Hout[((feat >> 3) * 64 + atom) * 8 + (feat & 7)] = (_Float16)v;
                }
            }
        }
    } else {
        float pe0 = 0.f, pe1 = 0.f;
#pragma unroll
        for (int f = 0; f < NFT; ++f) {
#pragma unroll
            for (int r = 0; r < 4; ++r) {
                int feat = fbase + f * 16 + l4 * 4 + r;
                float bb = bias[feat], ww = w4[feat];
                pe0 += celu_f(acc[f][0][r] + bb) * ww;
                pe1 += celu_f(acc[f][1][r] + bb) * ww;
            }
        }
        pe0 += __shfl_xor(pe0, 16); pe0 += __shfl_xor(pe0, 32);
        pe1 += __shfl_xor(pe1, 16); pe1 += __shfl_xor(pe1, 32);
        if (lane < 16) {
            atomicAdd(&L.eacc[abase + lane], pe0);
            atomicAdd(&L.eacc[abase + 16 + lane], pe1);
        }
    }
}

__global__ void __launch_bounds__(256, 2)
mlp_main(const int* __restrict__ counts, const int* __restrict__ bucket,
         const _Float16* __restrict__ aevh,
         const _Float16* __restrict__ wt1, const _Float16* __restrict__ wt2,
         const _Float16* __restrict__ wt3,
         const float* __restrict__ b1, const float* __restrict__ b2,
         const float* __restrict__ b3,
         const float* __restrict__ w4, const float* __restrict__ b4,
         float* __restrict__ out) {
    __shared__ LdsT L;
    const int s = blockIdx.y;
    const int cnt = counts[s];
    const int base = blockIdx.x * 64;
    if (base >= cnt) return;
    const int nval = min(64, cnt - base);
    const int tid = threadIdx.x;
    if (tid < 64) {
        int r = base + tid;
        if (r > cnt - 1) r = cnt - 1;
        L.idx[tid] = bucket[s * NATOMS + r];
        L.eacc[tid] = 0.f;
    }
    __syncthreads();
    const _Float16* xsrc = aevh + (size_t)L.idx[tid >> 2] * D_AEV;

    for (int e = 0; e < E_NUM; ++e) {
        int se = s * E_NUM + e;
        do_layer<H1W, D_AEV, true, false>(L, wt1 + (size_t)se * H1W * D_AEV, xsrc,
                                          nullptr, L.H1, b1 + se * H1W, nullptr, tid);
        do_layer<H2W, H1W, false, false>(L, wt2 + (size_t)se * H2W * H1W, nullptr,
                                         L.H1, L.H2, b2 + se * H2W, nullptr, tid);
        do_layer<H3W, H2W, false, true>(L, wt3 + (size_t)se * H3W * H2W, nullptr,
                                        L.H2, nullptr, b3 + se * H3W, w4 + se * H3W, tid);
    }
    __syncthreads();
    if (tid < 64) {
        float b4m = 0.f;
#pragma unroll
        for (int e = 0; e < E_NUM; ++e) b4m += b4[s * E_NUM + e];
        b4m *= 0.125f;
        float v = (tid < nval) ? (L.eacc[tid] * 0.125f + b4m) : 0.f;
#pragma unroll
        for (int off = 32; off > 0; off >>= 1) v += __shfl_down(v, off);
        if (tid == 0) atomicAdd(out, v);
    }
}

// ---------------- launcher ----------------

extern "C" void kernel_launch(void* const* d_in, const int* in_sizes, int n_in,
                              void* d_out, int out_size, void* d_ws, size_t ws_size,
                              hipStream_t stream) {
    const int*   species = (const int*)d_in[0];
    const float* aev = (const float*)d_in[1];
    const float* W1 = (const float*)d_in[2];
    const float* b1 = (const float*)d_in[3];
    const float* W2 = (const float*)d_in[4];
    const float* b2 = (const float*)d_in[5];
    const float* W3 = (const float*)d_in[6];
    const float* b3 = (const float*)d_in[7];
    const float* W4 = (const float*)d_in[8];
    const float* b4 = (const float*)d_in[9];
    float* out = (float*)d_out;

    char* ws = (char*)d_ws;
    int* counts = (int*)(ws + OFF_CNT);
    int* bucket = (int*)(ws + OFF_BUCKET);
    _Float16* aevh = (_Float16*)(ws + OFF_AEVH);
    _Float16* wt1 = (_Float16*)(ws + OFF_WT1);
    _Float16* wt2 = (_Float16*)(ws + OFF_WT2);
    _Float16* wt3 = (_Float16*)(ws + OFF_WT3);

    hipMemsetAsync(counts, 0, 256, stream);
    hipMemsetAsync(d_out, 0, sizeof(float) * out_size, stream);

    bucket_kernel<<<(NATOMS + 255) / 256, 256, 0, stream>>>(species, counts, bucket);
    cvt_aev_kernel<<<(NATOMS * D_AEV / 8 + 255) / 256, 256, 0, stream>>>(aev, aevh);
    transpose_cvt_kernel<<<dim3(H1W / 32, D_AEV / 32, S_NUM * E_NUM), dim3(32, 8), 0, stream>>>(W1, wt1, D_AEV, H1W);
    transpose_cvt_kernel<<<dim3(H2W / 32, H1W / 32, S_NUM * E_NUM), dim3(32, 8), 0, stream>>>(W2, wt2, H1W, H2W);
    transpose_cvt_kernel<<<dim3(H3W / 32, H2W / 32, S_NUM * E_NUM), dim3(32, 8), 0, stream>>>(W3, wt3, H2W, H3W);

    mlp_main<<<dim3((NATOMS + 63) / 64, S_NUM), 256, 0, stream>>>(
        counts, bucket, aevh, wt1, wt2, wt3, b1, b2, b3, W4, b4, out);
}

// Round 3
// 630.543 us; speedup vs baseline: 1.3146x; 1.3146x over previous
//
#include <hip/hip_runtime.h>

typedef _Float16 half8 __attribute__((ext_vector_type(8)));
typedef float f32x4 __attribute__((ext_vector_type(4)));

#define NATOMS 40000
#define D_AEV  384

constexpr int S_NUM = 4, E_NUM = 8;
constexpr int H1W = 160, H2W = 128, H3W = 96;
constexpr float ALPHA = 0.1f;
constexpr int NBLK = (NATOMS + 63) / 64;   // 625 atom-tiles per species

// ---- workspace layout (bytes) ----
constexpr size_t OFF_CNT    = 0;
constexpr size_t OFF_BUCKET = 256;
constexpr size_t OFF_PART   = OFF_BUCKET + (size_t)S_NUM * NATOMS * 4;   // 640256
constexpr size_t OFF_WT1    = (OFF_PART + (size_t)NBLK * S_NUM * 4 + 255) & ~(size_t)255;
constexpr size_t OFF_WT2    = OFF_WT1 + (size_t)S_NUM * E_NUM * H1W * D_AEV * 2;
constexpr size_t OFF_WT3    = OFF_WT2 + (size_t)S_NUM * E_NUM * H2W * H1W * 2;

// ---------------- helpers ----------------

__device__ __forceinline__ void gload_lds16(const _Float16* g, _Float16* l) {
    __builtin_amdgcn_global_load_lds((const __attribute__((address_space(1))) void*)g,
                                     (__attribute__((address_space(3))) void*)l, 16, 0, 0);
}

#define VMW(n) asm volatile("s_waitcnt vmcnt(" #n ")" ::: "memory")
#define BARR() do { asm volatile("" ::: "memory"); __builtin_amdgcn_s_barrier(); \
                    asm volatile("" ::: "memory"); } while (0)

__device__ __forceinline__ float celu_f(float x) {
    return x > 0.f ? x : fmaf(ALPHA, __expf(x * (1.f / ALPHA)), -ALPHA);
}

__device__ __forceinline__ f32x4 mfma16(half8 a, half8 b, f32x4 c) {
    return __builtin_amdgcn_mfma_f32_16x16x32_f16(a, b, c, 0, 0, 0);
}

// stage one W chunk: LDS layout [kgslot][OUTW][8] halfs, linear dest (wave-uniform+lane*16)
template <int NL>
__device__ __forceinline__ void stage(const _Float16* we, const int* vo, int c0, _Float16* buf) {
#pragma unroll
    for (int it = 0; it < NL; ++it)
        gload_lds16(we + vo[it] + c0, buf + ((size_t)threadIdx.x + it * 256) * 8);
}

// consume one chunk: KS k-steps, NFT feature tiles; A from regs, B from LDS
template <int OUTW, int NFT, int KS>
__device__ __forceinline__ void chunkc(const _Float16* buf, const half8* af,
                                       f32x4* acc, int l15, int l4) {
#pragma unroll
    for (int t = 0; t < KS; ++t) {
        half8 a = af[t];
#pragma unroll
        for (int f = 0; f < NFT; ++f) {
            half8 b = *(const half8*)&buf[(((t * 4 + l4) * OUTW) + f * 16 + l15) * 8];
            acc[f] = mfma16(a, b, acc[f]);
        }
    }
}

// ---------------- pre-kernels ----------------

__global__ void bucket_kernel(const int* __restrict__ species, int* __restrict__ counts,
                              int* __restrict__ bucket) {
    int i = blockIdx.x * 256 + threadIdx.x;
    if (i >= NATOMS) return;
    int s = species[i];
    int pos = atomicAdd(&counts[s], 1);
    bucket[s * NATOMS + pos] = i;
}

// in: [nmat][R][C] fp32  ->  out: [nmat][C][R] fp16   (R,C multiples of 32)
__global__ void transpose_cvt_kernel(const float* __restrict__ in, _Float16* __restrict__ out,
                                     int R, int C) {
    __shared__ float t[32][33];
    int m = blockIdx.z;
    const float* src = in + (size_t)m * R * C;
    _Float16* dst = out + (size_t)m * R * C;
    int c0 = blockIdx.x * 32, r0 = blockIdx.y * 32;
    int tx = threadIdx.x, ty = threadIdx.y;
#pragma unroll
    for (int j = 0; j < 32; j += 8)
        t[ty + j][tx] = src[(size_t)(r0 + ty + j) * C + c0 + tx];
    __syncthreads();
#pragma unroll
    for (int j = 0; j < 32; j += 8)
        dst[(size_t)(c0 + ty + j) * R + r0 + tx] = (_Float16)t[tx][ty + j];
}

// ---------------- main fused MLP kernel ----------------
// block = (species, 64-atom tile); 4 waves x 16 atoms; e-loop serial.
// A (activations) live in registers; W streamed global->LDS in 64-k chunks.

__global__ void __launch_bounds__(256, 2)
mlp_main(const int* __restrict__ counts, const int* __restrict__ bucket,
         const float* __restrict__ aev,
         const _Float16* __restrict__ wt1, const _Float16* __restrict__ wt2,
         const _Float16* __restrict__ wt3,
         const float* __restrict__ b1, const float* __restrict__ b2,
         const float* __restrict__ b3,
         const float* __restrict__ w4,
         float* __restrict__ partials) {
    __shared__ __align__(16) _Float16 Wb[2 * 8 * H1W * 8];   // 40 KB, double buffer
    __shared__ __align__(16) _Float16 scr[4][16 * 256];      // 32 KB, wave-private scratch
    __shared__ float part[4];

    const int s = blockIdx.y;
    const int flat = s * gridDim.x + blockIdx.x;
    const int cnt = counts[s];
    const int base = blockIdx.x * 64;
    const int tid = threadIdx.x;
    if (base >= cnt) { if (tid == 0) partials[flat] = 0.f; return; }

    const int l = tid & 63, w = tid >> 6;
    const int l15 = l & 15, l4 = l >> 4;
    char* sw = (char*)&scr[w][0];

    // ---- X prologue: 16 atoms/wave, A-frags in registers (48 VGPR) ----
    int aidx = bucket[s * NATOMS + min(base + w * 16 + l15, cnt - 1)];
    const float* xr = aev + (size_t)aidx * D_AEV + l4 * 8;
    half8 xa[12];
#pragma unroll
    for (int kk = 0; kk < 12; ++kk) {
        float4 f0 = *(const float4*)(xr + kk * 32);
        float4 f1 = *(const float4*)(xr + kk * 32 + 4);
        half8 h;
        h[0] = (_Float16)f0.x; h[1] = (_Float16)f0.y; h[2] = (_Float16)f0.z; h[3] = (_Float16)f0.w;
        h[4] = (_Float16)f1.x; h[5] = (_Float16)f1.y; h[6] = (_Float16)f1.z; h[7] = (_Float16)f1.w;
        xa[kk] = h;
    }

    // ---- staging address precompute (per layer, per thread) ----
    int vo1[5], vo2[4], vo3[3];
#pragma unroll
    for (int it = 0; it < 5; ++it) { int u = tid + it * 256; vo1[it] = (u % H1W) * D_AEV + (u / H1W) * 8; }
#pragma unroll
    for (int it = 0; it < 4; ++it) { int u = tid + it * 256; vo2[it] = (u & 127) * H1W + (u >> 7) * 8; }
#pragma unroll
    for (int it = 0; it < 3; ++it) { int u = tid + it * 256; vo3[it] = (u % H3W) * H2W + (u / H3W) * 8; }

    float eacc[4] = {0.f, 0.f, 0.f, 0.f};

    // prefetch e=0 layer1 chunk0 into buffer 0
    stage<5>(wt1 + (size_t)(s * E_NUM) * H1W * D_AEV, vo1, 0, Wb);

#pragma unroll 1
    for (int e = 0; e < E_NUM; ++e) {
        const int se = s * E_NUM + e;
        const _Float16* w1e = wt1 + (size_t)se * H1W * D_AEV;
        const _Float16* w2e = wt2 + (size_t)se * H2W * H1W;
        const _Float16* w3e = wt3 + (size_t)se * H3W * H2W;
        const _Float16* w1n = wt1 + (size_t)(se + (e < 7 ? 1 : 0)) * H1W * D_AEV;
        _Float16* bA = Wb + (e & 1) * (8 * H1W * 8);
        _Float16* bB = Wb + ((e & 1) ^ 1) * (8 * H1W * 8);

        f32x4 c1[10], c2[8], c3[6];
#pragma unroll
        for (int f = 0; f < 10; ++f) c1[f] = (f32x4){0.f, 0.f, 0.f, 0.f};
#pragma unroll
        for (int f = 0; f < 8; ++f) c2[f] = (f32x4){0.f, 0.f, 0.f, 0.f};
#pragma unroll
        for (int f = 0; f < 6; ++f) c3[f] = (f32x4){0.f, 0.f, 0.f, 0.f};
        half8 h1f[5], h2f[4];

        // ---- layer 1: 6 chunks of 64k ----
        stage<5>(w1e, vo1,  64, bB); VMW(5); BARR(); chunkc<H1W, 10, 2>(bA, &xa[0],  c1, l15, l4); BARR();
        stage<5>(w1e, vo1, 128, bA); VMW(5); BARR(); chunkc<H1W, 10, 2>(bB, &xa[2],  c1, l15, l4); BARR();
        stage<5>(w1e, vo1, 192, bB); VMW(5); BARR(); chunkc<H1W, 10, 2>(bA, &xa[4],  c1, l15, l4); BARR();
        stage<5>(w1e, vo1, 256, bA); VMW(5); BARR(); chunkc<H1W, 10, 2>(bB, &xa[6],  c1, l15, l4); BARR();
        stage<5>(w1e, vo1, 320, bB); VMW(5); BARR(); chunkc<H1W, 10, 2>(bA, &xa[8],  c1, l15, l4); BARR();
        stage<4>(w2e, vo2,   0, bA); VMW(4); BARR(); chunkc<H1W, 10, 2>(bB, &xa[10], c1, l15, l4); BARR();

        // ---- L1 epilogue: bias+celu -> scratch (XOR swizzle) -> H1 A-frags ----
        {
            const float* b1e = b1 + se * H1W;
#pragma unroll
            for (int f = 0; f < 10; ++f) {
                float bb = b1e[f * 16 + l15];
#pragma unroll
                for (int r = 0; r < 4; ++r) {
                    int atom = l4 * 4 + r;
                    float v = celu_f(c1[f][r] + bb);
                    int byte = atom * 512 + ((((f * 16 + l15) * 2)) ^ ((atom & 7) << 4));
                    *(_Float16*)(sw + byte) = (_Float16)v;
                }
            }
#pragma unroll
            for (int kk = 0; kk < 5; ++kk) {
                int byte = l15 * 512 + (((kk * 32 + l4 * 8) * 2) ^ ((l15 & 7) << 4));
                h1f[kk] = *(const half8*)(sw + byte);
            }
        }

        // ---- layer 2: chunks 64,64,32 ----
        stage<4>(w2e, vo2,  64, bB); VMW(4); BARR(); chunkc<H2W, 8, 2>(bA, &h1f[0], c2, l15, l4); BARR();
        stage<2>(w2e, vo2, 128, bA); VMW(2); BARR(); chunkc<H2W, 8, 2>(bB, &h1f[2], c2, l15, l4); BARR();
        stage<3>(w3e, vo3,   0, bB); VMW(3); BARR(); chunkc<H2W, 8, 1>(bA, &h1f[4], c2, l15, l4); BARR();

        // ---- L2 epilogue ----
        {
            const float* b2e = b2 + se * H2W;
#pragma unroll
            for (int f = 0; f < 8; ++f) {
                float bb = b2e[f * 16 + l15];
#pragma unroll
                for (int r = 0; r < 4; ++r) {
                    int atom = l4 * 4 + r;
                    float v = celu_f(c2[f][r] + bb);
                    int byte = atom * 512 + ((((f * 16 + l15) * 2)) ^ ((atom & 7) << 4));
                    *(_Float16*)(sw + byte) = (_Float16)v;
                }
            }
#pragma unroll
            for (int kk = 0; kk < 4; ++kk) {
                int byte = l15 * 512 + (((kk * 32 + l4 * 8) * 2) ^ ((l15 & 7) << 4));
                h2f[kk] = *(const half8*)(sw + byte);
            }
        }

        // ---- layer 3: 2 chunks; last phase prefetches next e's chunk0 ----
        stage<3>(w3e, vo3, 64, bA); VMW(3); BARR(); chunkc<H3W, 6, 2>(bB, &h2f[0], c3, l15, l4); BARR();
        stage<5>(w1n, vo1,  0, bB); VMW(5); BARR(); chunkc<H3W, 6, 2>(bA, &h2f[2], c3, l15, l4); BARR();

        // ---- L3 epilogue: dot with w4, butterfly over feat residues ----
        {
            const float* b3e = b3 + se * H3W;
            const float* w4e = w4 + se * H3W;
            float pe[4] = {0.f, 0.f, 0.f, 0.f};
#pragma unroll
            for (int f = 0; f < 6; ++f) {
                float bb = b3e[f * 16 + l15];
                float wv = w4e[f * 16 + l15];
#pragma unroll
                for (int r = 0; r < 4; ++r) pe[r] += celu_f(c3[f][r] + bb) * wv;
            }
#pragma unroll
            for (int m = 1; m < 16; m <<= 1) {
#pragma unroll
                for (int r = 0; r < 4; ++r) pe[r] += __shfl_xor(pe[r], m);
            }
#pragma unroll
            for (int r = 0; r < 4; ++r) eacc[r] += pe[r];
        }
    }

    // ---- block reduction: mask padded atoms, one partial per block ----
    float vsum = 0.f;
    if (l15 == 0) {
#pragma unroll
        for (int r = 0; r < 4; ++r) {
            int aib = w * 16 + l4 * 4 + r;
            if (base + aib < cnt) vsum += eacc[r];
        }
    }
    vsum += __shfl_xor(vsum, 16);
    vsum += __shfl_xor(vsum, 32);
    if (l == 0) part[w] = vsum;
    asm volatile("s_waitcnt lgkmcnt(0)" ::: "memory");
    __builtin_amdgcn_s_barrier();
    asm volatile("" ::: "memory");
    if (tid == 0) partials[flat] = (part[0] + part[1] + part[2] + part[3]) * 0.125f;
}

// ---------------- finalize ----------------

__global__ void finalize_kernel(const float* __restrict__ partials, const int* __restrict__ counts,
                                const float* __restrict__ b4, float* __restrict__ out) {
    __shared__ float wsum[4];
    float s = 0.f;
    for (int i = threadIdx.x; i < NBLK * S_NUM; i += 256) s += partials[i];
#pragma unroll
    for (int m = 1; m < 64; m <<= 1) s += __shfl_xor(s, m);
    if ((threadIdx.x & 63) == 0) wsum[threadIdx.x >> 6] = s;
    __syncthreads();
    if (threadIdx.x == 0) {
        float tot = wsum[0] + wsum[1] + wsum[2] + wsum[3];
        float bt = 0.f;
        for (int sp = 0; sp < S_NUM; ++sp) {
            float bs = 0.f;
            for (int e = 0; e < E_NUM; ++e) bs += b4[sp * E_NUM + e];
            bt += (float)counts[sp] * bs * 0.125f;
        }
        out[0] = tot + bt;
    }
}

// ---------------- launcher ----------------

extern "C" void kernel_launch(void* const* d_in, const int* in_sizes, int n_in,
                              void* d_out, int out_size, void* d_ws, size_t ws_size,
                              hipStream_t stream) {
    const int*   species = (const int*)d_in[0];
    const float* aev = (const float*)d_in[1];
    const float* W1 = (const float*)d_in[2];
    const float* b1 = (const float*)d_in[3];
    const float* W2 = (const float*)d_in[4];
    const float* b2 = (const float*)d_in[5];
    const float* W3 = (const float*)d_in[6];
    const float* b3 = (const float*)d_in[7];
    const float* W4 = (const float*)d_in[8];
    const float* b4 = (const float*)d_in[9];
    float* out = (float*)d_out;

    char* ws = (char*)d_ws;
    int* counts = (int*)(ws + OFF_CNT);
    int* bucket = (int*)(ws + OFF_BUCKET);
    float* partials = (float*)(ws + OFF_PART);
    _Float16* wt1 = (_Float16*)(ws + OFF_WT1);
    _Float16* wt2 = (_Float16*)(ws + OFF_WT2);
    _Float16* wt3 = (_Float16*)(ws + OFF_WT3);

    hipMemsetAsync(counts, 0, 256, stream);

    bucket_kernel<<<(NATOMS + 255) / 256, 256, 0, stream>>>(species, counts, bucket);
    transpose_cvt_kernel<<<dim3(H1W / 32, D_AEV / 32, S_NUM * E_NUM), dim3(32, 8), 0, stream>>>(W1, wt1, D_AEV, H1W);
    transpose_cvt_kernel<<<dim3(H2W / 32, H1W / 32, S_NUM * E_NUM), dim3(32, 8), 0, stream>>>(W2, wt2, H1W, H2W);
    transpose_cvt_kernel<<<dim3(H3W / 32, H2W / 32, S_NUM * E_NUM), dim3(32, 8), 0, stream>>>(W3, wt3, H2W, H3W);

    mlp_main<<<dim3(NBLK, S_NUM), 256, 0, stream>>>(
        counts, bucket, aev, wt1, wt2, wt3, b1, b2, b3, W4, partials);

    finalize_kernel<<<1, 256, 0, stream>>>(partials, counts, b4, out);
}

// Round 6
// 323.957 us; speedup vs baseline: 2.5587x; 1.9464x over previous
//
#include <hip/hip_runtime.h>

typedef _Float16 half8 __attribute__((ext_vector_type(8)));
typedef float f32x4 __attribute__((ext_vector_type(4)));

#define NATOMS 40000
#define D_AEV  384

constexpr int S_NUM = 4, E_NUM = 8;
constexpr int H1W = 160, H2W = 128, H3W = 96;
constexpr float ALPHA = 0.1f;
constexpr int NBLK = (NATOMS + 63) / 64;     // 625 atom-tiles per species
constexpr int HBLK = (NATOMS + 255) / 256;   // 157 histogram blocks

// ---- workspace layout (bytes) ----
constexpr size_t OFF_CNT    = 0;                                    // 4 ints
constexpr size_t OFF_BC     = 256;                                  // HBLK*4 ints
constexpr size_t OFF_BOFF   = OFF_BC + (size_t)HBLK * S_NUM * 4;
constexpr size_t OFF_BUCKET = (OFF_BOFF + (size_t)HBLK * S_NUM * 4 + 255) & ~(size_t)255;
constexpr size_t OFF_PART   = OFF_BUCKET + (size_t)S_NUM * NATOMS * 4;
constexpr size_t OFF_WT1    = (OFF_PART + (size_t)NBLK * S_NUM * 4 + 255) & ~(size_t)255;
constexpr size_t OFF_WT2    = OFF_WT1 + (size_t)S_NUM * E_NUM * H1W * D_AEV * 2;
constexpr size_t OFF_WT3    = OFF_WT2 + (size_t)S_NUM * E_NUM * H2W * H1W * 2;

// ---------------- helpers ----------------

__device__ __forceinline__ void gload_lds16(const _Float16* g, _Float16* l) {
    __builtin_amdgcn_global_load_lds((const __attribute__((address_space(1))) void*)g,
                                     (__attribute__((address_space(3))) void*)l, 16, 0, 0);
}

#define VMW(n) asm volatile("s_waitcnt vmcnt(" #n ")" ::: "memory")
#define BARR() do { asm volatile("" ::: "memory"); __builtin_amdgcn_s_barrier(); \
                    asm volatile("" ::: "memory"); } while (0)

__device__ __forceinline__ float celu_f(float x) {
    return x > 0.f ? x : fmaf(ALPHA, __expf(x * (1.f / ALPHA)), -ALPHA);
}

__device__ __forceinline__ f32x4 mfma16(half8 a, half8 b, f32x4 c) {
    return __builtin_amdgcn_mfma_f32_16x16x32_f16(a, b, c, 0, 0, 0);
}

__device__ __forceinline__ unsigned pk2(float a, float b) {
    auto p = __builtin_amdgcn_cvt_pkrtz(a, b);   // __fp16 ext_vector_type(2)
    unsigned u; __builtin_memcpy(&u, &p, 4); return u;
}

// stage one W chunk: LDS slot u <-> (kgroup = u / OUTW, feat = u % OUTW), linear dest
template <int NL>
__device__ __forceinline__ void stage(const _Float16* we, const int* vo, int c0, _Float16* buf) {
#pragma unroll
    for (int it = 0; it < NL; ++it)
        gload_lds16(we + vo[it] + c0, buf + ((size_t)threadIdx.x + it * 256) * 8);
}

// consume one chunk: A = W frag from LDS (row=feat), B = activations from regs (col=atom)
template <int OUTW, int KS, int NFT>
__device__ __forceinline__ void consume(const _Float16* buf, const half8* bf,
                                        f32x4* acc, int l15, int l4) {
    __builtin_amdgcn_s_setprio(1);
#pragma unroll
    for (int t = 0; t < KS; ++t) {
        half8 b = bf[t];
#pragma unroll
        for (int f = 0; f < NFT; ++f) {
            half8 a = *(const half8*)&buf[(((t * 4 + l4) * OUTW) + f * 16 + l15) * 8];
            acc[f] = mfma16(a, b, acc[f]);
        }
    }
    __builtin_amdgcn_s_setprio(0);
}

// cross-l4 repack: val[f*4+r] = celu'd D[feat=f*16+l4*4+r][atom=l15] -> B-frag half8
// for feats kk*32 + l4*8 + j  (j=0..7)
__device__ __forceinline__ half8 repack(const float* val, int kk, int l15, int l4) {
    unsigned p00 = pk2(val[(2 * kk) * 4 + 0], val[(2 * kk) * 4 + 1]);
    unsigned p01 = pk2(val[(2 * kk) * 4 + 2], val[(2 * kk) * 4 + 3]);
    unsigned p10 = pk2(val[(2 * kk + 1) * 4 + 0], val[(2 * kk + 1) * 4 + 1]);
    unsigned p11 = pk2(val[(2 * kk + 1) * 4 + 2], val[(2 * kk + 1) * 4 + 3]);
    int sA = l15 + ((l4 & 1) << 5);
    int sB = sA + 16;
    unsigned a0 = __shfl(p00, sA), b0 = __shfl(p10, sA);
    unsigned a1 = __shfl(p01, sA), b1 = __shfl(p11, sA);
    unsigned a2 = __shfl(p00, sB), b2 = __shfl(p10, sB);
    unsigned a3 = __shfl(p01, sB), b3 = __shfl(p11, sB);
    bool hi = (l4 >> 1) & 1;
    unsigned w[4];
    w[0] = hi ? b0 : a0; w[1] = hi ? b1 : a1; w[2] = hi ? b2 : a2; w[3] = hi ? b3 : a3;
    half8 r; __builtin_memcpy(&r, w, 16); return r;
}

// ---------------- bucket kernels (counting sort, no global contended atomics) ----

__global__ void hist_kernel(const int* __restrict__ species, int* __restrict__ bc) {
    __shared__ int h[S_NUM];
    int t = threadIdx.x;
    if (t < S_NUM) h[t] = 0;
    __syncthreads();
    int i = blockIdx.x * 256 + t;
    if (i < NATOMS) atomicAdd(&h[species[i]], 1);
    __syncthreads();
    if (t < S_NUM) bc[blockIdx.x * S_NUM + t] = h[t];
}

__global__ void scan_kernel(const int* __restrict__ bc, int* __restrict__ boff,
                            int* __restrict__ counts) {
    int w = threadIdx.x >> 6;    // species per wave
    int l = threadIdx.x & 63;
    int run = 0;
    for (int r = 0; r < (HBLK + 63) / 64; ++r) {
        int b = r * 64 + l;
        int v = (b < HBLK) ? bc[b * S_NUM + w] : 0;
        int x = v;
#pragma unroll
        for (int d = 1; d < 64; d <<= 1) { int y = __shfl_up(x, d); if (l >= d) x += y; }
        if (b < HBLK) boff[b * S_NUM + w] = run + x - v;
        run += __shfl(x, 63);
    }
    if (l == 0) counts[w] = run;
}

__global__ void scatter_kernel(const int* __restrict__ species, const int* __restrict__ boff,
                               int* __restrict__ bucket) {
    __shared__ int h[S_NUM];
    int t = threadIdx.x;
    if (t < S_NUM) h[t] = 0;
    __syncthreads();
    int i = blockIdx.x * 256 + t;
    if (i < NATOMS) {
        int sp = species[i];
        int r = atomicAdd(&h[sp], 1);
        bucket[sp * NATOMS + boff[blockIdx.x * S_NUM + sp] + r] = i;
    }
}

// in: [nmat][R][C] fp32  ->  out: [nmat][C][R] fp16
__global__ void transpose_cvt_kernel(const float* __restrict__ in, _Float16* __restrict__ out,
                                     int R, int C) {
    __shared__ float t[32][33];
    int m = blockIdx.z;
    const float* src = in + (size_t)m * R * C;
    _Float16* dst = out + (size_t)m * R * C;
    int c0 = blockIdx.x * 32, r0 = blockIdx.y * 32;
    int tx = threadIdx.x, ty = threadIdx.y;
#pragma unroll
    for (int j = 0; j < 32; j += 8)
        t[ty + j][tx] = src[(size_t)(r0 + ty + j) * C + c0 + tx];
    __syncthreads();
#pragma unroll
    for (int j = 0; j < 32; j += 8)
        dst[(size_t)(c0 + ty + j) * R + r0 + tx] = (_Float16)t[tx][ty + j];
}

// ---------------- main fused MLP kernel ----------------
// block = (species, 64-atom tile); 4 waves x 16 atoms (atom = col = lane&15).
// W streamed global->LDS, 12 chunks/ensemble, 3 buffers, prefetch depth 2.

__global__ void __launch_bounds__(256, 2)
mlp_main(const int* __restrict__ counts, const int* __restrict__ bucket,
         const float* __restrict__ aev,
         const _Float16* __restrict__ wt1, const _Float16* __restrict__ wt2,
         const _Float16* __restrict__ wt3,
         const float* __restrict__ b1, const float* __restrict__ b2,
         const float* __restrict__ b3,
         const float* __restrict__ w4,
         float* __restrict__ partials) {
    __shared__ __align__(16) _Float16 WB[3][8 * H1W * 8];   // 3 x 20KB
    __shared__ __align__(16) float Lbias[E_NUM * 480];      // 15KB: b1|b2|b3|w4 per e
    __shared__ float part[4];

    const int s = blockIdx.y;
    const int flat = s * gridDim.x + blockIdx.x;
    const int cnt = counts[s];
    const int base = blockIdx.x * 64;
    const int tid = threadIdx.x;
    if (base >= cnt) { if (tid == 0) partials[flat] = 0.f; return; }

    const int l = tid & 63, w = tid >> 6;
    const int l15 = l & 15, l4 = l >> 4;
    _Float16* B0 = WB[0]; _Float16* B1 = WB[1]; _Float16* B2 = WB[2];

    // ---- bias preload (once per block) ----
    for (int u = tid; u < E_NUM * 480; u += 256) {
        int e = u / 480, o = u % 480;
        int se = s * E_NUM + e;
        float v;
        if (o < 160)      v = b1[se * H1W + o];
        else if (o < 288) v = b2[se * H2W + (o - 160)];
        else if (o < 384) v = b3[se * H3W + (o - 288)];
        else              v = w4[se * H3W + (o - 384)];
        Lbias[u] = v;
    }
    __syncthreads();   // drains vmcnt+lgkmcnt: bias loads out of the pipeline queue

    // ---- X prologue: atom = w*16 + l15, k-cols l4*8 .. (+32 per chunk) ----
    int aidx = bucket[s * NATOMS + min(base + w * 16 + l15, cnt - 1)];
    const float* xr = aev + (size_t)aidx * D_AEV + l4 * 8;
    half8 xa[12];
#pragma unroll
    for (int kk = 0; kk < 12; ++kk) {
        float4 f0 = *(const float4*)(xr + kk * 32);
        float4 f1 = *(const float4*)(xr + kk * 32 + 4);
        half8 h;
        h[0] = (_Float16)f0.x; h[1] = (_Float16)f0.y; h[2] = (_Float16)f0.z; h[3] = (_Float16)f0.w;
        h[4] = (_Float16)f1.x; h[5] = (_Float16)f1.y; h[6] = (_Float16)f1.z; h[7] = (_Float16)f1.w;
        xa[kk] = h;
    }

    // ---- staging offsets ----
    int vo1[5], vo2[4], vo3[3];
#pragma unroll
    for (int it = 0; it < 5; ++it) { int u = tid + it * 256; vo1[it] = (u % H1W) * D_AEV + (u / H1W) * 8; }
#pragma unroll
    for (int it = 0; it < 4; ++it) { int u = tid + it * 256; vo2[it] = (u & 127) * H1W + (u >> 7) * 8; }
#pragma unroll
    for (int it = 0; it < 3; ++it) { int u = tid + it * 256; vo3[it] = (u % H3W) * H2W + (u / H3W) * 8; }

    float eacc = 0.f;

    // prologue: stage e0 chunks c0->B0, c1->B1
    {
        const _Float16* w1e0 = wt1 + (size_t)(s * E_NUM) * (H1W * D_AEV);
        stage<5>(w1e0, vo1, 0, B0);
        stage<5>(w1e0, vo1, 64, B1);
    }

#pragma unroll 1
    for (int e = 0; e < E_NUM; ++e) {
        const int se = s * E_NUM + e;
        const _Float16* w1e = wt1 + (size_t)se * (H1W * D_AEV);
        const _Float16* w2e = wt2 + (size_t)se * (H2W * H1W);
        const _Float16* w3e = wt3 + (size_t)se * (H3W * H2W);
        const _Float16* w1n = wt1 + (size_t)(se + (e < 7 ? 1 : 0)) * (H1W * D_AEV);
        const float* LB = Lbias + e * 480;

        f32x4 c1a[10], c2a[8], c3a[6];
#pragma unroll
        for (int f = 0; f < 10; ++f) c1a[f] = (f32x4){0.f, 0.f, 0.f, 0.f};
#pragma unroll
        for (int f = 0; f < 8; ++f) c2a[f] = (f32x4){0.f, 0.f, 0.f, 0.f};
#pragma unroll
        for (int f = 0; f < 6; ++f) c3a[f] = (f32x4){0.f, 0.f, 0.f, 0.f};
        half8 h1f[5], h2f[4];

        // ---- layer 1: chunks c0..c5 (64k each) ----
        stage<5>(w1e, vo1, 128, B2); VMW(10); BARR();
        consume<H1W, 2, 10>(B0, &xa[0], c1a, l15, l4); BARR();
        stage<5>(w1e, vo1, 192, B0); VMW(10); BARR();
        consume<H1W, 2, 10>(B1, &xa[2], c1a, l15, l4); BARR();
        stage<5>(w1e, vo1, 256, B1); VMW(10); BARR();
        consume<H1W, 2, 10>(B2, &xa[4], c1a, l15, l4); BARR();
        stage<5>(w1e, vo1, 320, B2); VMW(10); BARR();
        consume<H1W, 2, 10>(B0, &xa[6], c1a, l15, l4); BARR();
        stage<4>(w2e, vo2, 0, B0);   VMW(9);  BARR();
        consume<H1W, 2, 10>(B1, &xa[8], c1a, l15, l4); BARR();
        stage<2>(w2e, vo2, 64, B1);  VMW(6);  BARR();
        consume<H1W, 2, 10>(B2, &xa[10], c1a, l15, l4); BARR();

        // ---- L1 epilogue: bias+celu (reg) + cross-l4 repack -> h1f ----
        {
            float val[40];
#pragma unroll
            for (int f = 0; f < 10; ++f) {
                float4 bb = *(const float4*)&LB[f * 16 + l4 * 4];
#pragma unroll
                for (int r = 0; r < 4; ++r) val[f * 4 + r] = celu_f(c1a[f][r] + ((const float*)&bb)[r]);
            }
#pragma unroll
            for (int kk = 0; kk < 5; ++kk) h1f[kk] = repack(val, kk, l15, l4);
        }

        // ---- layer 2: c6 (64k), c7..c9 (32k) ----
        stage<2>(w2e, vo2, 96, B2);  VMW(4);  BARR();
        consume<H2W, 2, 8>(B0, &h1f[0], c2a, l15, l4); BARR();
        stage<2>(w2e, vo2, 128, B0); VMW(4);  BARR();
        consume<H2W, 1, 8>(B1, &h1f[2], c2a, l15, l4); BARR();
        stage<3>(w3e, vo3, 0, B1);   VMW(5);  BARR();
        consume<H2W, 1, 8>(B2, &h1f[3], c2a, l15, l4); BARR();
        stage<3>(w3e, vo3, 64, B2);  VMW(6);  BARR();
        consume<H2W, 1, 8>(B0, &h1f[4], c2a, l15, l4); BARR();

        // ---- L2 epilogue ----
        {
            float val[32];
#pragma unroll
            for (int f = 0; f < 8; ++f) {
                float4 bb = *(const float4*)&LB[160 + f * 16 + l4 * 4];
#pragma unroll
                for (int r = 0; r < 4; ++r) val[f * 4 + r] = celu_f(c2a[f][r] + ((const float*)&bb)[r]);
            }
#pragma unroll
            for (int kk = 0; kk < 4; ++kk) h2f[kk] = repack(val, kk, l15, l4);
        }

        // ---- layer 3: c10, c11 (64k); prefetch next e's c0,c1 ----
        if (e < 7) { stage<5>(w1n, vo1, 0, B0); VMW(8); } else { VMW(3); }
        BARR();
        consume<H3W, 2, 6>(B1, &h2f[0], c3a, l15, l4); BARR();
        if (e < 7) { stage<5>(w1n, vo1, 64, B1); VMW(10); } else { VMW(0); }
        BARR();
        consume<H3W, 2, 6>(B2, &h2f[2], c3a, l15, l4); BARR();

        // ---- L3 epilogue: dot with w4, reduce over l4 groups ----
        {
            float pe = 0.f;
#pragma unroll
            for (int f = 0; f < 6; ++f) {
                float4 bb = *(const float4*)&LB[288 + f * 16 + l4 * 4];
                float4 ww = *(const float4*)&LB[384 + f * 16 + l4 * 4];
#pragma unroll
                for (int r = 0; r < 4; ++r)
                    pe += celu_f(c3a[f][r] + ((const float*)&bb)[r]) * ((const float*)&ww)[r];
            }
            pe += __shfl_xor(pe, 16);
            pe += __shfl_xor(pe, 32);
            eacc += pe;
        }
    }

    // ---- block reduction ----
    float v = (l4 == 0 && (base + w * 16 + l15) < cnt) ? eacc : 0.f;
#pragma unroll
    for (int m = 1; m < 64; m <<= 1) v += __shfl_xor(v, m);
    if (l == 0) part[w] = v;
    __syncthreads();
    if (tid == 0) partials[flat] = (part[0] + part[1] + part[2] + part[3]) * 0.125f;
}

// ---------------- finalize ----------------

__global__ void finalize_kernel(const float* __restrict__ partials, const int* __restrict__ counts,
                                const float* __restrict__ b4, float* __restrict__ out) {
    __shared__ float wsum[4];
    float s = 0.f;
    for (int i = threadIdx.x; i < NBLK * S_NUM; i += 256) s += partials[i];
#pragma unroll
    for (int m = 1; m < 64; m <<= 1) s += __shfl_xor(s, m);
    if ((threadIdx.x & 63) == 0) wsum[threadIdx.x >> 6] = s;
    __syncthreads();
    if (threadIdx.x == 0) {
        float tot = wsum[0] + wsum[1] + wsum[2] + wsum[3];
        float bt = 0.f;
        for (int sp = 0; sp < S_NUM; ++sp) {
            float bs = 0.f;
            for (int e = 0; e < E_NUM; ++e) bs += b4[sp * E_NUM + e];
            bt += (float)counts[sp] * bs * 0.125f;
        }
        out[0] = tot + bt;
    }
}

// ---------------- launcher ----------------

extern "C" void kernel_launch(void* const* d_in, const int* in_sizes, int n_in,
                              void* d_out, int out_size, void* d_ws, size_t ws_size,
                              hipStream_t stream) {
    const int*   species = (const int*)d_in[0];
    const float* aev = (const float*)d_in[1];
    const float* W1 = (const float*)d_in[2];
    const float* b1 = (const float*)d_in[3];
    const float* W2 = (const float*)d_in[4];
    const float* b2 = (const float*)d_in[5];
    const float* W3 = (const float*)d_in[6];
    const float* b3 = (const float*)d_in[7];
    const float* W4 = (const float*)d_in[8];
    const float* b4 = (const float*)d_in[9];
    float* out = (float*)d_out;

    char* ws = (char*)d_ws;
    int* counts = (int*)(ws + OFF_CNT);
    int* bc     = (int*)(ws + OFF_BC);
    int* boff   = (int*)(ws + OFF_BOFF);
    int* bucket = (int*)(ws + OFF_BUCKET);
    float* partials = (float*)(ws + OFF_PART);
    _Float16* wt1 = (_Float16*)(ws + OFF_WT1);
    _Float16* wt2 = (_Float16*)(ws + OFF_WT2);
    _Float16* wt3 = (_Float16*)(ws + OFF_WT3);

    hist_kernel<<<HBLK, 256, 0, stream>>>(species, bc);
    scan_kernel<<<1, 256, 0, stream>>>(bc, boff, counts);
    scatter_kernel<<<HBLK, 256, 0, stream>>>(species, boff, bucket);
    transpose_cvt_kernel<<<dim3(H1W / 32, D_AEV / 32, S_NUM * E_NUM), dim3(32, 8), 0, stream>>>(W1, wt1, D_AEV, H1W);
    transpose_cvt_kernel<<<dim3(H2W / 32, H1W / 32, S_NUM * E_NUM), dim3(32, 8), 0, stream>>>(W2, wt2, H1W, H2W);
    transpose_cvt_kernel<<<dim3(H3W / 32, H2W / 32, S_NUM * E_NUM), dim3(32, 8), 0, stream>>>(W3, wt3, H2W, H3W);

    mlp_main<<<dim3(NBLK, S_NUM), 256, 0, stream>>>(
        counts, bucket, aev, wt1, wt2, wt3, b1, b2, b3, W4, partials);

    finalize_kernel<<<1, 256, 0, stream>>>(partials, counts, b4, out);
}

// Round 7
// 252.120 us; speedup vs baseline: 3.2877x; 1.2849x over previous
//
#include <hip/hip_runtime.h>

typedef _Float16 half8 __attribute__((ext_vector_type(8)));
typedef float f32x16 __attribute__((ext_vector_type(16)));

#define NATOMS 40000
#define D_AEV  384

constexpr int S_NUM = 4, E_NUM = 8;
constexpr int H1W = 160, H2W = 128, H3W = 96;
constexpr float ALPHA = 0.1f;
constexpr int HBLK = (NATOMS + 255) / 256;       // 157 histogram blocks
constexpr int TMAX = NATOMS / 128 + S_NUM + 1;   // 317 max 128-atom tiles
constexpr int GRID = 2 * TMAX;                   // 634 blocks (x2 ensemble halves)

// ---- workspace layout (bytes) ----
constexpr size_t OFF_CNT    = 0;
constexpr size_t OFF_BC     = 256;
constexpr size_t OFF_BOFF   = OFF_BC + (size_t)HBLK * S_NUM * 4;
constexpr size_t OFF_BUCKET = (OFF_BOFF + (size_t)HBLK * S_NUM * 4 + 255) & ~(size_t)255;
constexpr size_t OFF_PART   = OFF_BUCKET + (size_t)S_NUM * NATOMS * 4;
constexpr size_t OFF_WT1    = (OFF_PART + (size_t)GRID * 4 + 255) & ~(size_t)255;
constexpr size_t OFF_WT2    = OFF_WT1 + (size_t)S_NUM * E_NUM * H1W * D_AEV * 2;
constexpr size_t OFF_WT3    = OFF_WT2 + (size_t)S_NUM * E_NUM * H2W * H1W * 2;

// ---------------- helpers ----------------

__device__ __forceinline__ void gload_lds16(const _Float16* g, _Float16* l) {
    __builtin_amdgcn_global_load_lds((const __attribute__((address_space(1))) void*)g,
                                     (__attribute__((address_space(3))) void*)l, 16, 0, 0);
}

#define VMW(n) asm volatile("s_waitcnt vmcnt(" #n ")" ::: "memory")
#define BARR() do { asm volatile("" ::: "memory"); __builtin_amdgcn_s_barrier(); \
                    asm volatile("" ::: "memory"); } while (0)

__device__ __forceinline__ float celu_f(float x) {
    return x > 0.f ? x : fmaf(ALPHA, __expf(x * (1.f / ALPHA)), -ALPHA);
}

__device__ __forceinline__ unsigned pk2(float a, float b) {
    auto p = __builtin_amdgcn_cvt_pkrtz(a, b);
    unsigned u; __builtin_memcpy(&u, &p, 4); return u;
}

// stage one W chunk: LDS slot u <-> (kgroup = u / OUTW, feat = u % OUTW), linear dest
template <int NL>
__device__ __forceinline__ void stage(const _Float16* we, const int* vo, int c0, _Float16* buf) {
#pragma unroll
    for (int it = 0; it < NL; ++it)
        gload_lds16(we + vo[it] + c0, buf + ((size_t)threadIdx.x + it * 256) * 8);
}

// consume one chunk with 32x32x16: A = W from LDS (row=feat=l31, k=lhi*8+j),
// B = activations from regs (col=atom=l31). KS16 = 16-k steps, NFT = OUTW/32.
template <int OUTW, int KS16, int NFT>
__device__ __forceinline__ void consume32(const _Float16* buf, const half8* bf,
                                          f32x16* acc, int l31, int lhi) {
    __builtin_amdgcn_s_setprio(1);
#pragma unroll
    for (int t = 0; t < KS16; ++t) {
        half8 b = bf[t];
#pragma unroll
        for (int f = 0; f < NFT; ++f) {
            half8 a = *(const half8*)&buf[(((2 * t + lhi) * OUTW) + f * 32 + l31) * 8];
            acc[f] = __builtin_amdgcn_mfma_f32_32x32x16_f16(a, b, acc[f], 0, 0, 0);
        }
    }
    __builtin_amdgcn_s_setprio(0);
}

// bias+celu on C-tiles then repack to next-layer B-frags.
// C layout: col(atom)=l31, row(feat) = f*32 + (r&3) + 8*(r>>2) + 4*lhi.
// B-frag out[i]: feats [16i + lhi*8, +8) of the lane's atom.
template <int NFT>
__device__ __forceinline__ void epilogue(const f32x16* acc, const float* LB, int boff,
                                         int lhi, half8* out) {
#pragma unroll
    for (int f = 0; f < NFT; ++f) {
        float val[16];
#pragma unroll
        for (int rb = 0; rb < 4; ++rb) {
            float4 bb = *(const float4*)&LB[boff + f * 32 + rb * 8 + lhi * 4];
#pragma unroll
            for (int j = 0; j < 4; ++j)
                val[rb * 4 + j] = celu_f(acc[f][rb * 4 + j] + ((const float*)&bb)[j]);
        }
        unsigned wrd[8], xw[8];
#pragma unroll
        for (int i = 0; i < 8; ++i) wrd[i] = pk2(val[2 * i], val[2 * i + 1]);
#pragma unroll
        for (int i = 0; i < 8; ++i) xw[i] = __shfl_xor(wrd[i], 32);
        unsigned f0[4], f1[4];
#pragma unroll
        for (int i = 0; i < 2; ++i) {
            f0[i]     = lhi ? xw[2 + i]  : wrd[i];
            f0[2 + i] = lhi ? wrd[2 + i] : xw[i];
            f1[i]     = lhi ? xw[6 + i]  : wrd[4 + i];
            f1[2 + i] = lhi ? wrd[6 + i] : xw[4 + i];
        }
        __builtin_memcpy(&out[2 * f], f0, 16);
        __builtin_memcpy(&out[2 * f + 1], f1, 16);
    }
}

// ---------------- bucket kernels (counting sort) ----------------

__global__ void hist_kernel(const int* __restrict__ species, int* __restrict__ bc) {
    __shared__ int h[S_NUM];
    int t = threadIdx.x;
    if (t < S_NUM) h[t] = 0;
    __syncthreads();
    int i = blockIdx.x * 256 + t;
    if (i < NATOMS) atomicAdd(&h[species[i]], 1);
    __syncthreads();
    if (t < S_NUM) bc[blockIdx.x * S_NUM + t] = h[t];
}

__global__ void scan_kernel(const int* __restrict__ bc, int* __restrict__ boff,
                            int* __restrict__ counts) {
    int w = threadIdx.x >> 6;
    int l = threadIdx.x & 63;
    int run = 0;
    for (int r = 0; r < (HBLK + 63) / 64; ++r) {
        int b = r * 64 + l;
        int v = (b < HBLK) ? bc[b * S_NUM + w] : 0;
        int x = v;
#pragma unroll
        for (int d = 1; d < 64; d <<= 1) { int y = __shfl_up(x, d); if (l >= d) x += y; }
        if (b < HBLK) boff[b * S_NUM + w] = run + x - v;
        run += __shfl(x, 63);
    }
    if (l == 0) counts[w] = run;
}

__global__ void scatter_kernel(const int* __restrict__ species, const int* __restrict__ boff,
                               int* __restrict__ bucket) {
    __shared__ int h[S_NUM];
    int t = threadIdx.x;
    if (t < S_NUM) h[t] = 0;
    __syncthreads();
    int i = blockIdx.x * 256 + t;
    if (i < NATOMS) {
        int sp = species[i];
        int r = atomicAdd(&h[sp], 1);
        bucket[sp * NATOMS + boff[blockIdx.x * S_NUM + sp] + r] = i;
    }
}

// fused: [nmat][R][C] fp32 -> [nmat][C][R] fp16 for W1/W2/W3 in one launch
__global__ void transpose_all(const float* __restrict__ W1, const float* __restrict__ W2,
                              const float* __restrict__ W3, _Float16* __restrict__ wt1,
                              _Float16* __restrict__ wt2, _Float16* __restrict__ wt3) {
    __shared__ float t[32][33];
    int z = blockIdx.z;
    int m = z & 31;
    const float* src; _Float16* dst; int R, C;
    if (z < 32)      { src = W1; dst = wt1; R = D_AEV; C = H1W; }
    else if (z < 64) { src = W2; dst = wt2; R = H1W;  C = H2W; }
    else             { src = W3; dst = wt3; R = H2W;  C = H3W; }
    int c0 = blockIdx.x * 32, r0 = blockIdx.y * 32;
    if (c0 >= C || r0 >= R) return;
    src += (size_t)m * R * C;
    dst += (size_t)m * R * C;
    int tx = threadIdx.x, ty = threadIdx.y;
#pragma unroll
    for (int j = 0; j < 32; j += 8)
        t[ty + j][tx] = src[(size_t)(r0 + ty + j) * C + c0 + tx];
    __syncthreads();
#pragma unroll
    for (int j = 0; j < 32; j += 8)
        dst[(size_t)(c0 + ty + j) * R + r0 + tx] = (_Float16)t[tx][ty + j];
}

// ---------------- main fused MLP kernel ----------------
// block = (128-atom tile, 4-ensemble half); 4 waves x 32 atoms (atom = col = lane&31).
// W streamed global->LDS, 12 chunks/ensemble, 3 buffers, prefetch depth 2.

__global__ void __launch_bounds__(256, 2)
mlp_main(const int* __restrict__ counts, const int* __restrict__ bucket,
         const float* __restrict__ aev,
         const _Float16* __restrict__ wt1, const _Float16* __restrict__ wt2,
         const _Float16* __restrict__ wt3,
         const float* __restrict__ b1, const float* __restrict__ b2,
         const float* __restrict__ b3,
         const float* __restrict__ w4,
         float* __restrict__ partials) {
    __shared__ __align__(16) _Float16 WB[3][8 * H1W * 8];   // 3 x 20KB
    __shared__ __align__(16) float Lbias[4 * 480];          // 7.5KB: b1|b2|b3|w4 per local e
    __shared__ float part[4];

    const int bid = blockIdx.x;
    const int eb = bid & 1;          // ensemble half: e in [eb*4, eb*4+4)
    const int t = bid >> 1;          // atom-tile index (packed across species)
    const int tid = threadIdx.x;

    // ---- species resolution from counts prefix ----
    int cnt0 = counts[0], cnt1 = counts[1], cnt2 = counts[2], cnt3 = counts[3];
    int n0 = (cnt0 + 127) >> 7, n1 = (cnt1 + 127) >> 7, n2 = (cnt2 + 127) >> 7;
    int n3 = (cnt3 + 127) >> 7;
    int s, t0, cnt;
    if (t < n0)                { s = 0; t0 = t; cnt = cnt0; }
    else if (t < n0 + n1)      { s = 1; t0 = t - n0; cnt = cnt1; }
    else if (t < n0 + n1 + n2) { s = 2; t0 = t - n0 - n1; cnt = cnt2; }
    else if (t < n0 + n1 + n2 + n3) { s = 3; t0 = t - n0 - n1 - n2; cnt = cnt3; }
    else { if (tid == 0) partials[bid] = 0.f; return; }
    const int base = t0 * 128;

    const int l = tid & 63, w = tid >> 6;
    const int l31 = l & 31, lhi = l >> 5;
    _Float16* B0 = WB[0]; _Float16* B1 = WB[1]; _Float16* B2 = WB[2];

    // ---- bias preload (4 local ensembles) ----
    for (int u = tid; u < 4 * 480; u += 256) {
        int el = u / 480, o = u % 480;
        int se = s * E_NUM + eb * 4 + el;
        float v;
        if (o < 160)      v = b1[se * H1W + o];
        else if (o < 288) v = b2[se * H2W + (o - 160)];
        else if (o < 384) v = b3[se * H3W + (o - 288)];
        else              v = w4[se * H3W + (o - 384)];
        Lbias[u] = v;
    }
    __syncthreads();   // drains all counters before the pipelined section

    // ---- X prologue: atom = base + w*32 + l31; lane holds k = 16t + lhi*8 .. +8 ----
    int aidx = bucket[s * NATOMS + min(base + w * 32 + l31, cnt - 1)];
    const float* xr = aev + (size_t)aidx * D_AEV + lhi * 8;
    half8 xa[24];
#pragma unroll
    for (int kk = 0; kk < 24; ++kk) {
        float4 f0 = *(const float4*)(xr + kk * 16);
        float4 f1 = *(const float4*)(xr + kk * 16 + 4);
        half8 h;
        h[0] = (_Float16)f0.x; h[1] = (_Float16)f0.y; h[2] = (_Float16)f0.z; h[3] = (_Float16)f0.w;
        h[4] = (_Float16)f1.x; h[5] = (_Float16)f1.y; h[6] = (_Float16)f1.z; h[7] = (_Float16)f1.w;
        xa[kk] = h;
    }
    VMW(0);   // pin: all X loads retired before the counted-vmcnt ledger starts

    // ---- staging offsets ----
    int vo1[5], vo2[4], vo3[3];
#pragma unroll
    for (int it = 0; it < 5; ++it) { int u = tid + it * 256; vo1[it] = (u % H1W) * D_AEV + (u / H1W) * 8; }
#pragma unroll
    for (int it = 0; it < 4; ++it) { int u = tid + it * 256; vo2[it] = (u & 127) * H1W + (u >> 7) * 8; }
#pragma unroll
    for (int it = 0; it < 3; ++it) { int u = tid + it * 256; vo3[it] = (u % H3W) * H2W + (u / H3W) * 8; }

    float eacc = 0.f;
    const int se0 = s * E_NUM + eb * 4;

    // prologue: stage e0 chunks c0->B0, c1->B1
    {
        const _Float16* w1e0 = wt1 + (size_t)se0 * (H1W * D_AEV);
        stage<5>(w1e0, vo1, 0, B0);
        stage<5>(w1e0, vo1, 64, B1);
    }

#pragma unroll 1
    for (int el = 0; el < 4; ++el) {
        const int se = se0 + el;
        const _Float16* w1e = wt1 + (size_t)se * (H1W * D_AEV);
        const _Float16* w2e = wt2 + (size_t)se * (H2W * H1W);
        const _Float16* w3e = wt3 + (size_t)se * (H3W * H2W);
        const _Float16* w1n = wt1 + (size_t)(se + (el < 3 ? 1 : 0)) * (H1W * D_AEV);
        const float* LB = Lbias + el * 480;

        f32x16 c1a[5], c2a[4], c3a[3];
#pragma unroll
        for (int f = 0; f < 5; ++f) c1a[f] = (f32x16)(0.f);
#pragma unroll
        for (int f = 0; f < 4; ++f) c2a[f] = (f32x16)(0.f);
#pragma unroll
        for (int f = 0; f < 3; ++f) c3a[f] = (f32x16)(0.f);
        half8 h1f[10], h2f[8];

        // ---- layer 1: chunks c0..c5 (64k each) ----
        stage<5>(w1e, vo1, 128, B2); VMW(10); BARR();
        consume32<H1W, 4, 5>(B0, &xa[0], c1a, l31, lhi); BARR();
        stage<5>(w1e, vo1, 192, B0); VMW(10); BARR();
        consume32<H1W, 4, 5>(B1, &xa[4], c1a, l31, lhi); BARR();
        stage<5>(w1e, vo1, 256, B1); VMW(10); BARR();
        consume32<H1W, 4, 5>(B2, &xa[8], c1a, l31, lhi); BARR();
        stage<5>(w1e, vo1, 320, B2); VMW(10); BARR();
        consume32<H1W, 4, 5>(B0, &xa[12], c1a, l31, lhi); BARR();
        stage<4>(w2e, vo2, 0, B0);   VMW(9);  BARR();
        consume32<H1W, 4, 5>(B1, &xa[16], c1a, l31, lhi); BARR();
        stage<2>(w2e, vo2, 64, B1);  VMW(6);  BARR();
        consume32<H1W, 4, 5>(B2, &xa[20], c1a, l31, lhi); BARR();

        // ---- L1 epilogue ----
        epilogue<5>(c1a, LB, 0, lhi, h1f);

        // ---- layer 2: c6 (64k), c7..c9 (32k) ----
        stage<2>(w2e, vo2, 96, B2);  VMW(4);  BARR();
        consume32<H2W, 4, 4>(B0, &h1f[0], c2a, l31, lhi); BARR();
        stage<2>(w2e, vo2, 128, B0); VMW(4);  BARR();
        consume32<H2W, 2, 4>(B1, &h1f[4], c2a, l31, lhi); BARR();
        stage<3>(w3e, vo3, 0, B1);   VMW(5);  BARR();
        consume32<H2W, 2, 4>(B2, &h1f[6], c2a, l31, lhi); BARR();
        stage<3>(w3e, vo3, 64, B2);  VMW(6);  BARR();
        consume32<H2W, 2, 4>(B0, &h1f[8], c2a, l31, lhi); BARR();

        // ---- L2 epilogue ----
        epilogue<4>(c2a, LB, 160, lhi, h2f);

        // ---- layer 3: c10, c11 (64k); prefetch next e's c0,c1 ----
        if (el < 3) { stage<5>(w1n, vo1, 0, B0); VMW(8); } else { VMW(3); }
        BARR();
        consume32<H3W, 4, 3>(B1, &h2f[0], c3a, l31, lhi); BARR();
        if (el < 3) { stage<5>(w1n, vo1, 64, B1); VMW(10); } else { VMW(0); }
        BARR();
        consume32<H3W, 4, 3>(B2, &h2f[4], c3a, l31, lhi); BARR();

        // ---- L3 epilogue: dot with w4 ----
        {
            float pe = 0.f;
#pragma unroll
            for (int f = 0; f < 3; ++f) {
#pragma unroll
                for (int rb = 0; rb < 4; ++rb) {
                    float4 bb = *(const float4*)&LB[288 + f * 32 + rb * 8 + lhi * 4];
                    float4 ww = *(const float4*)&LB[384 + f * 32 + rb * 8 + lhi * 4];
#pragma unroll
                    for (int j = 0; j < 4; ++j)
                        pe += celu_f(c3a[f][rb * 4 + j] + ((const float*)&bb)[j]) * ((const float*)&ww)[j];
                }
            }
            pe += __shfl_xor(pe, 32);
            eacc += pe;
        }
    }

    // ---- block reduction (mask duplicate/padded atoms; lo half only) ----
    float v = (lhi == 0 && (base + w * 32 + l31) < cnt) ? eacc : 0.f;
#pragma unroll
    for (int m = 1; m < 64; m <<= 1) v += __shfl_xor(v, m);
    if (l == 0) part[w] = v;
    __syncthreads();
    if (tid == 0) partials[bid] = part[0] + part[1] + part[2] + part[3];
}

// ---------------- finalize ----------------

__global__ void finalize_kernel(const float* __restrict__ partials, const int* __restrict__ counts,
                                const float* __restrict__ b4, float* __restrict__ out) {
    __shared__ float wsum[4];
    float s = 0.f;
    for (int i = threadIdx.x; i < GRID; i += 256) s += partials[i];
#pragma unroll
    for (int m = 1; m < 64; m <<= 1) s += __shfl_xor(s, m);
    if ((threadIdx.x & 63) == 0) wsum[threadIdx.x >> 6] = s;
    __syncthreads();
    if (threadIdx.x == 0) {
        float tot = wsum[0] + wsum[1] + wsum[2] + wsum[3];
        float bt = 0.f;
        for (int sp = 0; sp < S_NUM; ++sp) {
            float bs = 0.f;
            for (int e = 0; e < E_NUM; ++e) bs += b4[sp * E_NUM + e];
            bt += (float)counts[sp] * bs;
        }
        out[0] = (tot + bt) * 0.125f;
    }
}

// ---------------- launcher ----------------

extern "C" void kernel_launch(void* const* d_in, const int* in_sizes, int n_in,
                              void* d_out, int out_size, void* d_ws, size_t ws_size,
                              hipStream_t stream) {
    const int*   species = (const int*)d_in[0];
    const float* aev = (const float*)d_in[1];
    const float* W1 = (const float*)d_in[2];
    const float* b1 = (const float*)d_in[3];
    const float* W2 = (const float*)d_in[4];
    const float* b2 = (const float*)d_in[5];
    const float* W3 = (const float*)d_in[6];
    const float* b3 = (const float*)d_in[7];
    const float* W4 = (const float*)d_in[8];
    const float* b4 = (const float*)d_in[9];
    float* out = (float*)d_out;

    char* ws = (char*)d_ws;
    int* counts = (int*)(ws + OFF_CNT);
    int* bc     = (int*)(ws + OFF_BC);
    int* boff   = (int*)(ws + OFF_BOFF);
    int* bucket = (int*)(ws + OFF_BUCKET);
    float* partials = (float*)(ws + OFF_PART);
    _Float16* wt1 = (_Float16*)(ws + OFF_WT1);
    _Float16* wt2 = (_Float16*)(ws + OFF_WT2);
    _Float16* wt3 = (_Float16*)(ws + OFF_WT3);

    hist_kernel<<<HBLK, 256, 0, stream>>>(species, bc);
    scan_kernel<<<1, 256, 0, stream>>>(bc, boff, counts);
    scatter_kernel<<<HBLK, 256, 0, stream>>>(species, boff, bucket);
    transpose_all<<<dim3(5, 12, 96), dim3(32, 8), 0, stream>>>(W1, W2, W3, wt1, wt2, wt3);

    mlp_main<<<GRID, 256, 0, stream>>>(
        counts, bucket, aev, wt1, wt2, wt3, b1, b2, b3, W4, partials);

    finalize_kernel<<<1, 256, 0, stream>>>(partials, counts, b4, out);
}